// Round 5
// baseline (1030.230 us; speedup 1.0000x reference)
//
#include <hip/hip_runtime.h>

#define N 128
#define NITER 60
#define PST 132      // partial-row stride (floats): multiple of 4 -> 16B-aligned rows for b128
#define COLOFF 2128  // colpart base offset: 16*PST=2112 rounded so COLOFF%32==16 (bank shift)
#define YOFF 132     // yvB offset: %8==4 -> copy-B readers land on disjoint bank quads; %4==0 (16B aligned)

typedef float v2f __attribute__((ext_vector_type(2)));
typedef float v4f __attribute__((ext_vector_type(4)));

// Round-4 structure (1 row/block, b128 publish, paired reduce) with two fixes
// driven by the r4 counters:
//  - SQ_LDS_BANK_CONFLICT was bit-identical r0 vs r4 (2.388e7) despite the
//    publish/reduce rewrite -> the source is the ec2 read (yv at 32B stride,
//    banks 8tc%32 = 4-way). Fix: duplicate y into yvB at +132 floats
//    (bank offset +4); lanes with (tc>>2)&1 read copy B -> every bank quad
//    serves 2 addresses = 2-way = free.
//  - VALU-busy cycles implied ~2x the modeled instruction count: scalar
//    fmed3f forced unpack/clamp/repack of every v2f pair. Replaced with
//    elementwise max/min (v_pk_max_f32 / v_pk_min_f32) -> the whole update
//    chain stays packed. For w>=0 and finite t, min(max(t,-w),w) is bitwise
//    identical to fmed3(t,-w,w).
// All float ops and summation orders remain bitwise-identical to round 0.
__global__ __launch_bounds__(256, 1)
void gfusedmax_kernel(const float* __restrict__ x,
                      const float* __restrict__ A,
                      float* __restrict__ out)
{
    const int b   = blockIdx.x;
    const int tid = threadIdx.x;
    const int tr  = tid >> 4;   // 0..15
    const int tc  = tid & 15;   // 0..15
    const int i0  = tr * 8;
    const int j0  = tc * 8;

    __shared__ __align__(16) float parts[COLOFF + 16 * PST];  // rowpart @0, colpart @COLOFF
    __shared__ __align__(16) float yvbuf[YOFF + N];           // yvA @0, yvB @YOFF
    __shared__ float sorted[N];
    __shared__ float red[8];

    float* const yvA = yvbuf;
    float* const yvB = yvbuf + YOFF;

    const float step = 1.0f / 256.0f;   // 1/(2N), exact power of two

    // ---- load w = lam*A (lam=1) tile as pairs, init z=0 ----
    v2f w2[8][4];
    v2f z2[8][4];
    const float* Ab = A + (size_t)b * N * N;
    #pragma unroll
    for (int r = 0; r < 8; ++r) {
        const v4f* src = (const v4f*)(Ab + (size_t)(i0 + r) * N + j0);
        v4f p0 = src[0];
        v4f p1 = src[1];
        w2[r][0] = p0.lo; w2[r][1] = p0.hi;
        w2[r][2] = p1.lo; w2[r][3] = p1.hi;
        #pragma unroll
        for (int cp = 0; cp < 4; ++cp) z2[r][cp] = (v2f)0.0f;
    }

    // x value for the y this thread's PAIR computes (m = tid>>1)
    const int m = tid >> 1;
    const float xm = x[(size_t)b * N + m];
    // per-lane partial base: even lanes sum rowparts, odd lanes colparts
    const float* pb = parts + ((tid & 1) ? COLOFF : 0);
    // ec2 source copy: alternate bank-quad groups read the shifted copy
    const float* ecb = ((tc >> 2) & 1) ? yvB : yvA;

    v2f pr2[8], pc2[4];
    #pragma unroll
    for (int r = 0; r < 8; ++r) pr2[r] = (v2f)0.0f;
    #pragma unroll
    for (int cp = 0; cp < 4; ++cp) pc2[cp] = (v2f)0.0f;

    for (int it = 0; it <= NITER; ++it) {
        // (a) publish partials as b128 (even bank-window distribution)
        v4f r0, r1, c0, c1;
        r0.x = pr2[0].x + pr2[0].y;  r0.y = pr2[1].x + pr2[1].y;
        r0.z = pr2[2].x + pr2[2].y;  r0.w = pr2[3].x + pr2[3].y;
        r1.x = pr2[4].x + pr2[4].y;  r1.y = pr2[5].x + pr2[5].y;
        r1.z = pr2[6].x + pr2[6].y;  r1.w = pr2[7].x + pr2[7].y;
        c0.x = pc2[0].x; c0.y = pc2[0].y; c0.z = pc2[1].x; c0.w = pc2[1].y;
        c1.x = pc2[2].x; c1.y = pc2[2].y; c1.z = pc2[3].x; c1.w = pc2[3].y;
        *(v4f*)&parts[tc * PST + i0]              = r0;
        *(v4f*)&parts[tc * PST + i0 + 4]          = r1;
        *(v4f*)&parts[COLOFF + tr * PST + j0]     = c0;
        *(v4f*)&parts[COLOFF + tr * PST + j0 + 4] = c1;
        __syncthreads();

        // (b) paired reduce: even lane = rowsum(y[m]), odd lane = colsum(y[m]).
        // Sequential k order matches round 0 bitwise. Banks: even (4k+m)%32,
        // odd (4k+m+16)%32 -> uniform 2-way (free).
        float acc = 0.0f;
        #pragma unroll
        for (int k = 0; k < 16; ++k) acc += pb[k * PST + m];
        float other = __shfl_xor(acc, 1, 64);
        if (!(tid & 1)) {
            float y = (xm - acc) + other;   // (x - rs) + cs, same order as round 0
            // scaling by 2^-8 is exact, so step*yi - step*yj == step*(yi-yj)
            float yo = (it == NITER) ? y : step * y;
            yvA[m] = yo;
            yvB[m] = yo;                    // bank-shifted copy for ec2 readers
        }
        __syncthreads();
        if (it == NITER) break;

        // (c) fully-packed dual update + partial-sum accumulation
        v2f drs[8], ec2[4];
        #pragma unroll
        for (int r = 0; r < 8; ++r) drs[r] = (v2f)yvA[i0 + r];  // 16-lane broadcast
        v4f e0 = *(const v4f*)&ecb[j0];
        v4f e1 = *(const v4f*)&ecb[j0 + 4];
        ec2[0] = e0.lo; ec2[1] = e0.hi;
        ec2[2] = e1.lo; ec2[3] = e1.hi;
        #pragma unroll
        for (int r = 0; r < 8; ++r) {
            #pragma unroll
            for (int cp = 0; cp < 4; ++cp) {
                v2f t  = (z2[r][cp] + drs[r]) - ec2[cp];       // 2x v_pk_add_f32
                v2f wv = w2[r][cp];
                // clamp == fmed3(t,-w,w) for finite t, w>=0; stays packed:
                v2f zn = __builtin_elementwise_min(
                             __builtin_elementwise_max(t, -wv), wv);
                z2[r][cp] = zn;
                pr2[r]  = (cp == 0) ? zn : pr2[r] + zn;        // v_pk_add_f32
                pc2[cp] = (r == 0)  ? zn : pc2[cp] + zn;       // v_pk_add_f32
            }
        }
    }

    // ---- sparsemax over yvA[0..127] (raw y) ----
    float v = 0.0f;
    if (tid < N) {
        v = yvA[tid];
        int rk = 0;
        for (int k = 0; k < N; ++k) {
            float u = yvA[k];
            rk += (u > v) || (u == v && k < tid);
        }
        sorted[rk] = v;   // rank is a permutation (ties broken by index)
    }
    __syncthreads();

    float s = 0.0f, csum = 0.0f;
    if (tid < N) {
        s = sorted[tid];
        for (int mm = 0; mm < N; ++mm) {         // uniform index -> LDS broadcast
            float t = sorted[mm];
            if (mm <= tid) csum += t;            // inclusive prefix at sorted pos
        }
    }
    bool mask = (tid < N) && (1.0f + (float)(tid + 1) * s > csum);
    float aRed = mask ? s : 0.0f;
    float bRed = mask ? 1.0f : 0.0f;
    #pragma unroll
    for (int off = 32; off >= 1; off >>= 1) {
        aRed += __shfl_down(aRed, off, 64);
        bRed += __shfl_down(bRed, off, 64);
    }
    const int wid = tid >> 6;
    if ((tid & 63) == 0) { red[wid * 2] = aRed; red[wid * 2 + 1] = bRed; }
    __syncthreads();
    const float tau = (red[0] + red[2] + red[4] + red[6] - 1.0f)
                    / (red[1] + red[3] + red[5] + red[7]);
    if (tid < N) out[(size_t)b * N + tid] = fmaxf(v - tau, 0.0f);
}

extern "C" void kernel_launch(void* const* d_in, const int* in_sizes, int n_in,
                              void* d_out, int out_size, void* d_ws, size_t ws_size,
                              hipStream_t stream) {
    const float* x = (const float*)d_in[0];
    const float* A = (const float*)d_in[1];
    float* out = (float*)d_out;
    const int B = in_sizes[0] / N;   // 4096 rows
    gfusedmax_kernel<<<B, 256, 0, stream>>>(x, A, out);
}

// Round 6
// 931.342 us; speedup vs baseline: 1.1062x; 1.1062x over previous
//
#include <hip/hip_runtime.h>

#define N 128
#define NITER 60
#define RPS 132                  // partial stride (floats): mult of 4 -> b128-aligned rows
#define COLBASE (32 * RPS + 16)  // colpart base: %4==0 (align), %32==16 (disjoint bank halves)

typedef float v2f __attribute__((ext_vector_type(2)));
typedef float v4f __attribute__((ext_vector_type(4)));

// 512 threads/block, 32 elements/thread (8 rows x 4 cols). Rationale (r4/r5
// counters): r4's 64-el/thread state (z+w = 128f + temps ~ 190 V+AGPRs) forced
// the 256-reg quantum -> 2 waves/SIMD -> barrier bubbles capped VALUBusy at 64%.
// Halving per-thread state (~105 regs, enforced by __launch_bounds__(512,4),
// cap 128) doubles resident waves to 4/SIMD. The 4-col tile also makes every
// LDS access conflict-floor: publish b128s spread 8 lanes per bank-window
// (8 clk = wave64 floor), ec read yv[4tc] touches all 32 banks, reduce is
// uniform 2-way (free, m136). fmed3 restored (r5: min/max = +73% VALU issue).
// SQ_LDS_BANK_CONFLICT ~2.4e7 is the benign 2-way floor - not a target.
__global__ __launch_bounds__(512, 4)
void gfusedmax_kernel(const float* __restrict__ x,
                      const float* __restrict__ A,
                      float* __restrict__ out)
{
    const int b   = blockIdx.x;
    const int tid = threadIdx.x;
    const int tr  = tid >> 5;   // 0..15 -> rows 8tr..8tr+7
    const int tc  = tid & 31;   // 0..31 -> cols 4tc..4tc+3
    const int i0  = tr * 8;
    const int j0  = tc * 4;

    __shared__ __align__(16) float parts[COLBASE + 16 * RPS]; // rowpart@0 (32 grp), colpart@COLBASE (16 grp)
    __shared__ __align__(16) float yv[N];
    __shared__ float sorted[N];
    __shared__ float red[16];

    const float step = 1.0f / 256.0f;   // 1/(2N), exact power of two

    // ---- load w = lam*A (lam=1) tile: 8 rows x 4 cols, as v2f pairs ----
    v2f w2[8][2];
    v2f z2[8][2];
    const float* Ab = A + (size_t)b * N * N;
    #pragma unroll
    for (int r = 0; r < 8; ++r) {
        v4f p = *(const v4f*)(Ab + (size_t)(i0 + r) * N + j0);
        w2[r][0] = p.lo; w2[r][1] = p.hi;
        z2[r][0] = (v2f)0.0f; z2[r][1] = (v2f)0.0f;
    }

    // reduce role: lane quad (q=tid&3) computes y[m], m=tid>>2.
    //  q0: rowpart groups 0..15, q1: rowpart 16..31,
    //  q2,q3: colpart 0..15 (IDENTICAL addrs -> LDS broadcast, no extra banks;
    //         pair-sum yields 2C, halved exactly by 0.5f).
    const int m = tid >> 2;
    const int q = tid & 3;
    const float xm = x[(size_t)b * N + m];
    const float* pb = parts + ((q == 0) ? m
                         : (q == 1) ? (16 * RPS + m)
                                    : (COLBASE + m));

    float rowp[8];      // per-row partials (published at loop head; zeros at it=0)
    v2f   pc2[2];       // per-col partials
    #pragma unroll
    for (int r = 0; r < 8; ++r) rowp[r] = 0.0f;
    pc2[0] = (v2f)0.0f; pc2[1] = (v2f)0.0f;

    for (int it = 0; it <= NITER; ++it) {
        // (a) publish partials: 2 b128 (row) + 1 b128 (col), all at bank floor
        v4f r0v, r1v, c0v;
        r0v.x = rowp[0]; r0v.y = rowp[1]; r0v.z = rowp[2]; r0v.w = rowp[3];
        r1v.x = rowp[4]; r1v.y = rowp[5]; r1v.z = rowp[6]; r1v.w = rowp[7];
        c0v.x = pc2[0].x; c0v.y = pc2[0].y; c0v.z = pc2[1].x; c0v.w = pc2[1].y;
        *(v4f*)&parts[tc * RPS + i0]           = r0v;
        *(v4f*)&parts[tc * RPS + i0 + 4]       = r1v;
        *(v4f*)&parts[COLBASE + tr * RPS + j0] = c0v;
        __syncthreads();

        // (b) quad reduce: 16 strided reads each (q0/q1 share 16 banks 2-way,
        // q2/q3 broadcast on the other 16 -> 2 clk/step, free).
        float acc = 0.0f;
        #pragma unroll
        for (int k = 0; k < 16; ++k) acc += pb[k * RPS];
        float acc2  = acc + __shfl_xor(acc, 1, 64);   // q0|q1: R ; q2|q3: 2C
        float other = __shfl_xor(acc2, 2, 64);        // q0 receives 2C
        if (q == 0) {
            float y = (xm - acc2) + 0.5f * other;     // (x - rowsum) + colsum
            // 2^-8 scaling is exact: step*yi - step*yj == step*(yi - yj)
            yv[m] = (it == NITER) ? y : step * y;
        }
        __syncthreads();
        if (it == NITER) break;

        // (c) packed dual update + partial accumulation (fmed3 clamp)
        v4f ev = *(const v4f*)&yv[j0];                // cols j0..j0+3: banks 4tc..4tc+3
        v2f ec0, ec1;
        ec0 = ev.lo; ec1 = ev.hi;
        #pragma unroll
        for (int r = 0; r < 8; ++r) {
            v2f dr = (v2f)yv[i0 + r];                 // 2-addr broadcast per wave
            v2f t0 = (z2[r][0] + dr) - ec0;
            v2f t1 = (z2[r][1] + dr) - ec1;
            v2f wv0 = w2[r][0], wv1 = w2[r][1];
            v2f zn0, zn1;
            zn0.x = __builtin_amdgcn_fmed3f(t0.x, -wv0.x, wv0.x);
            zn0.y = __builtin_amdgcn_fmed3f(t0.y, -wv0.y, wv0.y);
            zn1.x = __builtin_amdgcn_fmed3f(t1.x, -wv1.x, wv1.x);
            zn1.y = __builtin_amdgcn_fmed3f(t1.y, -wv1.y, wv1.y);
            z2[r][0] = zn0;
            z2[r][1] = zn1;
            v2f pr = zn0 + zn1;
            rowp[r] = pr.x + pr.y;
            pc2[0] += zn0;
            pc2[1] += zn1;
        }
    }

    // ---- sparsemax over yv[0..127] (raw y); threads >=128 idle but sync ----
    float v = 0.0f;
    if (tid < N) {
        v = yv[tid];
        int rk = 0;
        for (int k = 0; k < N; ++k) {
            float u = yv[k];
            rk += (u > v) || (u == v && k < tid);
        }
        sorted[rk] = v;   // rank is a permutation (ties broken by index)
    }
    __syncthreads();

    float s = 0.0f, csum = 0.0f;
    if (tid < N) {
        s = sorted[tid];
        for (int mm = 0; mm < N; ++mm) {          // uniform index -> LDS broadcast
            float t = sorted[mm];
            if (mm <= tid) csum += t;             // inclusive prefix at sorted pos
        }
    }
    bool mask = (tid < N) && (1.0f + (float)(tid + 1) * s > csum);
    float aRed = mask ? s : 0.0f;
    float bRed = mask ? 1.0f : 0.0f;
    #pragma unroll
    for (int off = 32; off >= 1; off >>= 1) {
        aRed += __shfl_down(aRed, off, 64);
        bRed += __shfl_down(bRed, off, 64);
    }
    const int wid = tid >> 6;                      // 0..7; only 0,1 hold data
    if ((tid & 63) == 0) { red[wid * 2] = aRed; red[wid * 2 + 1] = bRed; }
    __syncthreads();
    const float tau = (red[0] + red[2] - 1.0f) / (red[1] + red[3]);
    if (tid < N) out[(size_t)b * N + tid] = fmaxf(v - tau, 0.0f);
}

extern "C" void kernel_launch(void* const* d_in, const int* in_sizes, int n_in,
                              void* d_out, int out_size, void* d_ws, size_t ws_size,
                              hipStream_t stream) {
    const float* x = (const float*)d_in[0];
    const float* A = (const float*)d_in[1];
    float* out = (float*)d_out;
    const int B = in_sizes[0] / N;   // 4096 rows
    gfusedmax_kernel<<<B, 512, 0, stream>>>(x, A, out);
}